// Round 8
// baseline (3593.782 us; speedup 1.0000x reference)
//
#include <hip/hip_runtime.h>
#include <hip/hip_bf16.h>
#include <stdint.h>

typedef __attribute__((ext_vector_type(8))) short bf16x8;
typedef __attribute__((ext_vector_type(4))) float f32x4;
typedef __attribute__((ext_vector_type(4))) unsigned int u32x4;
typedef unsigned long long ull_t;

#define S_LEN 512
#define B_DIM 64
#define E_DIM 512
#define H_DIM 768
#define G4    3072      // 4H (one direction's gate width)
#define H2    1536      // 2H (combined hs row)
#define M_ROWS 32768    // S*B
#define CHUNK 128       // seq steps per X-chunk
#define CM    8192      // CHUNK*B rows per chunk
#define SLW   24        // cols per slice
#define WPS   8         // published words per slice per row
#define WPR   256       // packed words per h row (256*3 = 768 cols)
#define RWRD  4096      // words per ring per parity (16 rows * 256)
#define PSTR  16384     // words per parity (4 rings)
#define KRES  640       // K columns resident in LDS (fwd scan)
#define KREG  4         // K-tail tiles in registers (fwd scan)
#define WROW  648       // padded LDS weight row, fwd (shorts)
#define NTILES 1536     // X-GEMM tiles per chunk (64 m x 24 n)
#define EROW  520       // padded 512-k row (shorts) for bwd fused GEMM

__device__ __forceinline__ float sigmf_(float x) { return 1.0f / (1.0f + __expf(-x)); }
__device__ __forceinline__ float tanhf2(float x) {
  x = fminf(fmaxf(x, -20.0f), 20.0f);
  float e = __expf(2.0f * x);
  return (e - 1.0f) / (e + 1.0f);
}
__device__ __forceinline__ float bfu(unsigned short u) { return __uint_as_float((unsigned)u << 16); }
__device__ __forceinline__ unsigned short packbf(float a) {
  __hip_bfloat16 t = __float2bfloat16(a);
  unsigned short b;
  __builtin_memcpy(&b, &t, 2);
  return b;
}

// ---------------- embedding gather + cast to bf16 ----------------
__global__ __launch_bounds__(256) void k_gather(const int* __restrict__ tokens,
                                                const float* __restrict__ emb,
                                                __hip_bfloat16* __restrict__ out) {
  const int t = blockIdx.x * 256 + threadIdx.x;
  const int e0 = t * 8;
  const int row = e0 >> 9;
  const int k = e0 & 511;
  const int tok = tokens[row];
  const float4* p = (const float4*)(emb + (size_t)tok * E_DIM + k);
  const float4 v0 = p[0], v1 = p[1];
  __align__(16) __hip_bfloat16 tmp[8];
  tmp[0] = __float2bfloat16(v0.x); tmp[1] = __float2bfloat16(v0.y);
  tmp[2] = __float2bfloat16(v0.z); tmp[3] = __float2bfloat16(v0.w);
  tmp[4] = __float2bfloat16(v1.x); tmp[5] = __float2bfloat16(v1.y);
  tmp[6] = __float2bfloat16(v1.z); tmp[7] = __float2bfloat16(v1.w);
  *(bf16x8*)(out + (size_t)t * 8) = *(const bf16x8*)tmp;
}

// ---------------- fp32 -> bf16 transpose (LDS tiled): dst[c*Rs+r]=src[r*Cs+c] ----------------
__global__ __launch_bounds__(256) void k_transpose_cast(const float* __restrict__ src,
                                                        __hip_bfloat16* __restrict__ dst,
                                                        int Rs, int Cs) {
  __shared__ float tile[32][33];
  const int tx = threadIdx.x & 31, ty = threadIdx.x >> 5;
  const int c0 = blockIdx.x * 32, r0 = blockIdx.y * 32;
  #pragma unroll
  for (int i = ty; i < 32; i += 8)
    tile[i][tx] = src[(size_t)(r0 + i) * Cs + c0 + tx];
  __syncthreads();
  #pragma unroll
  for (int i = ty; i < 32; i += 8)
    dst[(size_t)(c0 + i) * Rs + r0 + tx] = __float2bfloat16(tile[tx][i]);
}

// ---------------- combined bias for one direction: bi + bh ----------------
__global__ __launch_bounds__(256) void k_bias(const float* __restrict__ bi,
                                              const float* __restrict__ bh,
                                              float* __restrict__ bias) {
  const int n = blockIdx.x * 256 + threadIdx.x;
  bias[n] = bi[n] + bh[n];
}

// ---------------- X-GEMM tile, pre-gathered bf16 A (fast path) --------
__device__ __forceinline__ void gemm_tile_e(char* pool, int tile,
                                            const __hip_bfloat16* __restrict__ A,
                                            const __hip_bfloat16* __restrict__ BT,
                                            const float* __restrict__ bias,
                                            __hip_bfloat16* __restrict__ C) {
  auto As = (__hip_bfloat16 (*)[40])pool;
  auto Bs = (__hip_bfloat16 (*)[40])(pool + 10240);
  const int tid = threadIdx.x;
  const int wave = tid >> 6, lane = tid & 63;
  const int q = lane >> 4, lr = lane & 15;
  const int wm = (wave >> 1) * 64, wn = (wave & 1) * 64;
  const int nb = tile % 24, mb = tile / 24;
  const int m0 = mb * 128, n0 = nb * 128;
  const int srow = tid >> 2, skseg = (tid & 3) * 8;

  f32x4 acc[4][4];
  #pragma unroll
  for (int i = 0; i < 4; ++i)
    #pragma unroll
    for (int j = 0; j < 4; ++j) { f32x4 z = {0.f, 0.f, 0.f, 0.f}; acc[i][j] = z; }

  for (int kt = 0; kt < 16; ++kt) {
    __syncthreads();
    const int kbase = kt * 32 + skseg;
    *(bf16x8*)&As[srow][skseg]      = *(const bf16x8*)(A + (size_t)(m0 + srow) * E_DIM + kbase);
    *(bf16x8*)&As[srow + 64][skseg] = *(const bf16x8*)(A + (size_t)(m0 + srow + 64) * E_DIM + kbase);
    *(bf16x8*)&Bs[srow][skseg]      = *(const bf16x8*)(BT + (size_t)(n0 + srow) * E_DIM + kbase);
    *(bf16x8*)&Bs[srow + 64][skseg] = *(const bf16x8*)(BT + (size_t)(n0 + srow + 64) * E_DIM + kbase);
    __syncthreads();
    bf16x8 af[4], bfr[4];
    #pragma unroll
    for (int mt = 0; mt < 4; ++mt) af[mt] = *(const bf16x8*)&As[wm + mt * 16 + lr][q * 8];
    #pragma unroll
    for (int nt = 0; nt < 4; ++nt) bfr[nt] = *(const bf16x8*)&Bs[wn + nt * 16 + lr][q * 8];
    #pragma unroll
    for (int mt = 0; mt < 4; ++mt)
      #pragma unroll
      for (int nt = 0; nt < 4; ++nt)
        acc[mt][nt] = __builtin_amdgcn_mfma_f32_16x16x32_bf16(af[mt], bfr[nt], acc[mt][nt], 0, 0, 0);
  }
  #pragma unroll
  for (int mt = 0; mt < 4; ++mt) {
    #pragma unroll
    for (int nt = 0; nt < 4; ++nt) {
      const int col = n0 + wn + nt * 16 + lr;
      const float bv = bias[col];
      #pragma unroll
      for (int i = 0; i < 4; ++i) {
        const int row = m0 + wm + mt * 16 + q * 4 + i;
        C[(size_t)row * G4 + col] = __float2bfloat16(acc[mt][nt][i] + bv);
      }
    }
  }
}

// ---------------- X-GEMM tile with fused embedding gather (fallback tiers) ----------------
__device__ __forceinline__ void gemm_tile_g(char* pool, int tile,
                                            const int* __restrict__ tokens_c,
                                            const float* __restrict__ emb,
                                            const __hip_bfloat16* __restrict__ BT,
                                            const float* __restrict__ bias,
                                            __hip_bfloat16* __restrict__ C) {
  auto As = (__hip_bfloat16 (*)[40])pool;
  auto Bs = (__hip_bfloat16 (*)[40])(pool + 10240);
  const int tid = threadIdx.x;
  const int wave = tid >> 6, lane = tid & 63;
  const int q = lane >> 4, lr = lane & 15;
  const int wm = (wave >> 1) * 64, wn = (wave & 1) * 64;
  const int nb = tile % 24, mb = tile / 24;
  const int m0 = mb * 128, n0 = nb * 128;
  const int srow = tid >> 2, skseg = (tid & 3) * 8;
  const int tok0 = tokens_c[m0 + srow];
  const int tok1 = tokens_c[m0 + srow + 64];

  f32x4 acc[4][4];
  #pragma unroll
  for (int i = 0; i < 4; ++i)
    #pragma unroll
    for (int j = 0; j < 4; ++j) { f32x4 z = {0.f, 0.f, 0.f, 0.f}; acc[i][j] = z; }

  for (int kt = 0; kt < 16; ++kt) {
    __syncthreads();
    const int kbase = kt * 32 + skseg;
    {
      const float* ap = emb + (size_t)tok0 * E_DIM + kbase;
      const float4 v0 = *(const float4*)ap, v1 = *(const float4*)(ap + 4);
      __align__(16) __hip_bfloat16 t8[8];
      t8[0] = __float2bfloat16(v0.x); t8[1] = __float2bfloat16(v0.y);
      t8[2] = __float2bfloat16(v0.z); t8[3] = __float2bfloat16(v0.w);
      t8[4] = __float2bfloat16(v1.x); t8[5] = __float2bfloat16(v1.y);
      t8[6] = __float2bfloat16(v1.z); t8[7] = __float2bfloat16(v1.w);
      *(bf16x8*)&As[srow][skseg] = *(const bf16x8*)t8;
    }
    {
      const float* ap = emb + (size_t)tok1 * E_DIM + kbase;
      const float4 v0 = *(const float4*)ap, v1 = *(const float4*)(ap + 4);
      __align__(16) __hip_bfloat16 t8[8];
      t8[0] = __float2bfloat16(v0.x); t8[1] = __float2bfloat16(v0.y);
      t8[2] = __float2bfloat16(v0.z); t8[3] = __float2bfloat16(v0.w);
      t8[4] = __float2bfloat16(v1.x); t8[5] = __float2bfloat16(v1.y);
      t8[6] = __float2bfloat16(v1.z); t8[7] = __float2bfloat16(v1.w);
      *(bf16x8*)&As[srow + 64][skseg] = *(const bf16x8*)t8;
    }
    *(bf16x8*)&Bs[srow][skseg]      = *(const bf16x8*)(BT + (size_t)(n0 + srow) * E_DIM + kbase);
    *(bf16x8*)&Bs[srow + 64][skseg] = *(const bf16x8*)(BT + (size_t)(n0 + srow + 64) * E_DIM + kbase);
    __syncthreads();
    bf16x8 af[4], bfr[4];
    #pragma unroll
    for (int mt = 0; mt < 4; ++mt) af[mt] = *(const bf16x8*)&As[wm + mt * 16 + lr][q * 8];
    #pragma unroll
    for (int nt = 0; nt < 4; ++nt) bfr[nt] = *(const bf16x8*)&Bs[wn + nt * 16 + lr][q * 8];
    #pragma unroll
    for (int mt = 0; mt < 4; ++mt)
      #pragma unroll
      for (int nt = 0; nt < 4; ++nt)
        acc[mt][nt] = __builtin_amdgcn_mfma_f32_16x16x32_bf16(af[mt], bfr[nt], acc[mt][nt], 0, 0, 0);
  }
  #pragma unroll
  for (int mt = 0; mt < 4; ++mt) {
    #pragma unroll
    for (int nt = 0; nt < 4; ++nt) {
      const int col = n0 + wn + nt * 16 + lr;
      const float bv = bias[col];
      #pragma unroll
      for (int i = 0; i < 4; ++i) {
        const int row = m0 + wm + mt * 16 + q * 4 + i;
        C[(size_t)row * G4 + col] = __float2bfloat16(acc[mt][nt][i] + bv);
      }
    }
  }
}

// ---------------- standalone X-GEMMs ----------------
__global__ __launch_bounds__(256) void k_gemm_e(const __hip_bfloat16* __restrict__ A,
                                                const __hip_bfloat16* __restrict__ BT,
                                                const float* __restrict__ bias,
                                                __hip_bfloat16* __restrict__ C) {
  __shared__ __align__(16) char pool[20480];
  gemm_tile_e(pool, blockIdx.x, A, BT, bias, C);
}
__global__ __launch_bounds__(256) void k_gemm_g(const int* __restrict__ tokens_c,
                                                const float* __restrict__ emb,
                                                const __hip_bfloat16* __restrict__ BT,
                                                const float* __restrict__ bias,
                                                __hip_bfloat16* __restrict__ C) {
  __shared__ __align__(16) char pool[20480];
  gemm_tile_g(pool, blockIdx.x, tokens_c, emb, BT, bias, C);
}

// ---------------- output block of 8 rows ----------------
__device__ __forceinline__ void out_block8(char* pool, int ob,
                                           const __hip_bfloat16* __restrict__ Hs,
                                           const float* __restrict__ Wout,
                                           const float* __restrict__ bout,
                                           const int* __restrict__ tokens,
                                           float* __restrict__ out) {
  auto rowbuf = (float (*)[1536])pool;
  const int r0 = ob * 8;
  const int tid = threadIdx.x;
  for (int idx = tid; idx < 8 * 1536; idx += 256) {
    const int rr = idx / 1536, k = idx % 1536;
    rowbuf[rr][k] = __bfloat162float(Hs[(size_t)(r0 + rr) * H2 + k]);
  }
  __syncthreads();
  const int l = tid & 31, rr = tid >> 5;
  float acc = bout[l];
  #pragma unroll 8
  for (int k = 0; k < 1536; ++k) acc += rowbuf[rr][k] * Wout[k * 32 + l];
  const int row = r0 + rr;
  if (l == 0 && tokens[row] == 1) acc += 10000.0f;
  out[(size_t)row * 32 + l] = acc;
  __syncthreads();   // rowbuf reused by next iteration
}

__global__ __launch_bounds__(256) void k_out(const __hip_bfloat16* __restrict__ Hs,
                                             const float* __restrict__ Wout,
                                             const float* __restrict__ bout,
                                             const int* __restrict__ tokens,
                                             float* __restrict__ out) {
  __shared__ __align__(16) char pool[49152];
  out_block8(pool, blockIdx.x, Hs, Wout, bout, tokens, out);
}

// ---------------- forward scan (+ co-scheduled next-chunk X-GEMM workers) ----------------
__global__ __launch_bounds__(256, 1) void k_fwd_fused(const __hip_bfloat16* __restrict__ X,
                                                      const __hip_bfloat16* __restrict__ WhTf,
                                                      ull_t* __restrict__ hbuf,
                                                      __hip_bfloat16* __restrict__ Hs,
                                                      float* __restrict__ cstate,
                                                      float* __restrict__ hT,
                                                      int chunk,
                                                      const __hip_bfloat16* __restrict__ EmbA,
                                                      const int* __restrict__ tokens_nx,
                                                      const float* __restrict__ emb,
                                                      const __hip_bfloat16* __restrict__ WiT_nx,
                                                      const float* __restrict__ Bias_nx,
                                                      __hip_bfloat16* __restrict__ Xw) {
  __shared__ __align__(16) char pool[155904];
  const int bx = blockIdx.x;

  if (bx >= 128) {                       // ---- GEMM worker role ----
    const int nw = gridDim.x - 128;
    if (EmbA) {
      for (int t = bx - 128; t < NTILES; t += nw)
        gemm_tile_e(pool, t, EmbA, WiT_nx, Bias_nx, Xw);
    } else {
      for (int t = bx - 128; t < NTILES; t += nw)
        gemm_tile_g(pool, t, tokens_nx, emb, WiT_nx, Bias_nx, Xw);
    }
    return;
  }

  // ---- scan role: identical to the verified R4 kernel ----
  unsigned short* wlds = (unsigned short*)pool;                       // 124,416 B
  auto h_stage = (unsigned short (*)[776])(pool + 124416);            //  24,832 B
  auto g_lds   = (float (*)[16][26])(pool + 149248);                  //   6,656 B

  const int group = bx >> 5;
  const int slice = bx & 31;
  const int r0 = group * 16;
  const int j0 = slice * SLW;
  const int tid = threadIdx.x;
  const int w = tid >> 6;
  const int lane = tid & 63;
  const int q = lane >> 4, lr = lane & 15;
  const int base = chunk * CHUNK;

  const int prow = tid >> 4;
  const int pw   = tid & 15;

  const int row  = tid >> 3;
  const int wloc = tid & 7;
  const int col0 = 3 * wloc;

  for (int c = tid; c < 96 * (KRES / 8); c += 256) {
    const int r = c / (KRES / 8), k8 = c % (KRES / 8);
    const int gate = r / SLW, n = r % SLW;
    const float4 v = *(const float4*)(WhTf + (size_t)(gate * H_DIM + j0 + n) * H_DIM + k8 * 8);
    *(float4*)(wlds + (size_t)r * WROW + k8 * 8) = v;
  }

  const int wn0 = lr;
  const int wn1 = 16 + (lr & 7);
  bf16x8 wr0[KREG], wr1[KREG];
  #pragma unroll
  for (int kk = 0; kk < KREG; ++kk) {
    const int ko = KRES + kk * 32 + q * 8;
    wr0[kk] = *(const bf16x8*)(WhTf + (size_t)(w * H_DIM + j0 + wn0) * H_DIM + ko);
    wr1[kk] = *(const bf16x8*)(WhTf + (size_t)(w * H_DIM + j0 + wn1) * H_DIM + ko);
  }

  float cr[3] = {0.f, 0.f, 0.f};
  if (tid < 128) {
    const float* cs = cstate + (size_t)(r0 + row) * H_DIM + j0 + col0;
    cr[0] = cs[0]; cr[1] = cs[1]; cr[2] = cs[2];
  }

  const unsigned skipbit = ((pw >> 2) == (slice & 3)) ? (1u << (slice >> 2)) : 0u;

  __syncthreads();

  for (int s = 0; s < CHUNK; ++s) {
    const int gs = base + s;

    unsigned short xs[4][3];
    if (tid < 128) {
      const unsigned short* xp = (const unsigned short*)(X + ((size_t)s * B_DIM + r0 + row) * G4 + j0 + col0);
      #pragma unroll
      for (int g = 0; g < 4; ++g)
        #pragma unroll
        for (int j = 0; j < 3; ++j) xs[g][j] = xp[g * H_DIM + j];
    }

    const ull_t* hc = hbuf + ((size_t)(gs & 1)) * PSTR + (size_t)group * RWRD
                    + (size_t)prow * WPR + 2 * pw;
    u32x4 d0 = {0,0,0,0}, d1 = {0,0,0,0}, d2 = {0,0,0,0}, d3 = {0,0,0,0};
    u32x4 d4 = {0,0,0,0}, d5 = {0,0,0,0}, d6 = {0,0,0,0}, d7 = {0,0,0,0};
    const unsigned pollmask = (s == 0) ? 0xFFu : (0xFFu ^ skipbit);
    {
      const unsigned e16 = (unsigned)(unsigned short)gs;
      unsigned need = pollmask;
      long guard = 0;
      for (;;) {
#define POLL_LD(i, dv) \
        if (need & (1u << (i))) \
          asm volatile("global_load_dwordx4 %0, %1, off sc0 sc1" \
                       : "=v"(dv) : "v"(hc + 32 * (i)) : "memory");
        POLL_LD(0, d0) POLL_LD(1, d1) POLL_LD(2, d2) POLL_LD(3, d3)
        POLL_LD(4, d4) POLL_LD(5, d5) POLL_LD(6, d6) POLL_LD(7, d7)
#undef POLL_LD
        asm volatile("s_waitcnt vmcnt(0)"
                     : "+v"(d0), "+v"(d1), "+v"(d2), "+v"(d3),
                       "+v"(d4), "+v"(d5), "+v"(d6), "+v"(d7)
                     :: "memory");
        unsigned nn = 0;
#define POLL_CK(i, dv) \
        if ((need & (1u << (i))) && \
            ((((dv).x & 0xFFFFu) != e16) || (((dv).z & 0xFFFFu) != e16))) nn |= 1u << (i);
        POLL_CK(0, d0) POLL_CK(1, d1) POLL_CK(2, d2) POLL_CK(3, d3)
        POLL_CK(4, d4) POLL_CK(5, d5) POLL_CK(6, d6) POLL_CK(7, d7)
#undef POLL_CK
        need = nn;
        if (!need) break;
        if (++guard > (1L << 20)) break;
        __builtin_amdgcn_s_sleep(1);
      }
    }
    {
#define STAGE_PAIR(i, dv) \
      if (pollmask & (1u << (i))) { \
        unsigned* hp = (unsigned*)&h_stage[prow][6 * pw + 96 * (i)]; \
        hp[0] = ((dv).x >> 16) | ((dv).y << 16); \
        hp[1] = ((dv).y >> 16) | ((dv).z & 0xFFFF0000u); \
        hp[2] = (dv).w; \
      }
      STAGE_PAIR(0, d0) STAGE_PAIR(1, d1) STAGE_PAIR(2, d2) STAGE_PAIR(3, d3)
      STAGE_PAIR(4, d4) STAGE_PAIR(5, d5) STAGE_PAIR(6, d6) STAGE_PAIR(7, d7)
#undef STAGE_PAIR
    }
    __syncthreads();   // B1: h staged

    f32x4 acc0 = {0.f, 0.f, 0.f, 0.f};
    f32x4 acc1 = {0.f, 0.f, 0.f, 0.f};
    {
      const unsigned short* wb = wlds + (size_t)w * SLW * WROW;
      #pragma unroll
      for (int kt = 0; kt < KRES / 32; ++kt) {
        const int ko = kt * 32 + q * 8;
        const bf16x8 a  = *(const bf16x8*)&h_stage[lr][ko];
        const bf16x8 b0 = *(const bf16x8*)(wb + (size_t)wn0 * WROW + ko);
        const bf16x8 b1 = *(const bf16x8*)(wb + (size_t)wn1 * WROW + ko);
        acc0 = __builtin_amdgcn_mfma_f32_16x16x32_bf16(a, b0, acc0, 0, 0, 0);
        acc1 = __builtin_amdgcn_mfma_f32_16x16x32_bf16(a, b1, acc1, 0, 0, 0);
      }
      #pragma unroll
      for (int kk = 0; kk < KREG; ++kk) {
        const bf16x8 a = *(const bf16x8*)&h_stage[lr][KRES + kk * 32 + q * 8];
        acc0 = __builtin_amdgcn_mfma_f32_16x16x32_bf16(a, wr0[kk], acc0, 0, 0, 0);
        acc1 = __builtin_amdgcn_mfma_f32_16x16x32_bf16(a, wr1[kk], acc1, 0, 0, 0);
      }
    }
    #pragma unroll
    for (int i = 0; i < 4; ++i) g_lds[w][q * 4 + i][lr] = acc0[i];
    if (lr < 8) {
      #pragma unroll
      for (int i = 0; i < 4; ++i) g_lds[w][q * 4 + i][16 + lr] = acc1[i];
    }
    __syncthreads();   // B2: gates ready

    if (tid < 128) {
      float h[3];
      #pragma unroll
      for (int j = 0; j < 3; ++j) {
        const float rv = g_lds[0][row][col0 + j] + bfu(xs[0][j]);
        const float fv = g_lds[1][row][col0 + j] + bfu(xs[1][j]);
        const float gv = g_lds[2][row][col0 + j] + bfu(xs[2][j]);
        const float ov = g_lds[3][row][col0 + j] + bfu(xs[3][j]);
        const float c = sigmf_(fv) * cr[j] + sigmf_(rv) * tanhf2(gv);
        cr[j] = c;
        h[j] = sigmf_(ov) * tanhf2(c);
      }
      const unsigned short b0 = packbf(h[0]), b1 = packbf(h[1]), b2 = packbf(h[2]);
      const ull_t wv = (ull_t)(unsigned short)(gs + 1)
                     | ((ull_t)b0 << 16) | ((ull_t)b1 << 32) | ((ull_t)b2 << 48);
      __hip_atomic_store(hbuf + ((size_t)((gs + 1) & 1)) * PSTR + (size_t)group * RWRD
                         + (size_t)row * WPR + slice * WPS + wloc,
                         wv, __ATOMIC_RELAXED, __HIP_MEMORY_SCOPE_AGENT);
      h_stage[row][j0 + col0]     = b0;
      h_stage[row][j0 + col0 + 1] = b1;
      h_stage[row][j0 + col0 + 2] = b2;
      unsigned short* hsp = (unsigned short*)(Hs + ((size_t)gs * B_DIM + r0 + row) * H2 + j0 + col0);
      hsp[0] = b0; hsp[1] = b1; hsp[2] = b2;
      if (chunk == 3 && s == CHUNK - 1) {
        float* hp = hT + (size_t)(r0 + row) * H_DIM + j0 + col0;
        hp[0] = h[0]; hp[1] = h[1]; hp[2] = h[2];
      }
    }
  }

  if (tid < 128) {
    float* cs = cstate + (size_t)(r0 + row) * H_DIM + j0 + col0;
    cs[0] = cr[0]; cs[1] = cr[1]; cs[2] = cr[2];
  }
}

// ---------------- hTW[b,n] = hT[b,:] @ Wh_b[:,n] ----------------
__global__ __launch_bounds__(256) void k_hTW(const float* __restrict__ hT,
                                             const float* __restrict__ Whb,
                                             float* __restrict__ hTW) {
  const int b = blockIdx.y;
  const int n = blockIdx.x * 256 + threadIdx.x;
  __shared__ float hs[768];
  for (int i = threadIdx.x; i < 768; i += 256) hs[i] = hT[b * 768 + i];
  __syncthreads();
  float acc = 0.f;
  #pragma unroll 4
  for (int k = 0; k < 768; ++k) acc += hs[k] * Whb[(size_t)k * G4 + n];
  hTW[(size_t)b * G4 + n] = acc;
}

// ---------------- fused backward: on-the-fly gate GEMM + scan (no X materialization) ----
// 128 scan blocks (4 b-groups x 32 slices of 24 cols) + 128 out-projection workers.
// Per scan block: Wi_b slice (4 gates x 24 cols x 512 k) LDS-resident once; per
// descending 2-step group: stage 32 emb rows -> MFMA GEMM (m-tiles = steps, B
// reused across m) -> nonlin + c2 + Hs write. No inter-block deps; 1 barrier/step.
// Saves the 100 MB/chunk X_b HBM round trip that bound R5-R7's backward phase.
__global__ __launch_bounds__(256, 1) void k_bwd_fused2(const __hip_bfloat16* __restrict__ Emb,  // [32768,512] bf16
                                                       const __hip_bfloat16* __restrict__ WiTb, // [3072,512]
                                                       const float* __restrict__ BiasB,         // [3072]
                                                       const float* __restrict__ hTW,           // [64,3072]
                                                       __hip_bfloat16* __restrict__ Hs,
                                                       float* __restrict__ c2state,             // [64,768]
                                                       int chunk, int out_chunk,
                                                       const float* __restrict__ Wout,
                                                       const float* __restrict__ bout,
                                                       const int* __restrict__ tokens,
                                                       float* __restrict__ out) {
  __shared__ __align__(16) char pool[146432];
  const int bx = blockIdx.x;

  if (bx >= 128) {                     // ---- output workers (128) ----
    if (out_chunk >= 0)
      for (int ob = bx - 128; ob < 1024; ob += 128)
        out_block8(pool, out_chunk * 1024 + ob, Hs, Wout, bout, tokens, out);
    return;
  }

  // ---- fused GEMM+scan role ----
  unsigned short* wlds = (unsigned short*)pool;                 // 96 x EROW shorts = 99,840 B
  auto emb_s = (unsigned short (*)[EROW])(pool + 99840);        // 32 x EROW shorts = 33,280 B
  auto g_lds = (float (*)[2][16][26])(pool + 133120);           // [4][2][16][26] = 13,312 B

  const int group = bx >> 5;           // batch rows [16g, 16g+16)
  const int slice = bx & 31;           // cols [24*slice, 24*slice+24)
  const int r0 = group * 16;
  const int j0 = slice * SLW;
  const int tid = threadIdx.x;
  const int w = tid >> 6;              // wave = gate (r,f,g,o)
  const int lane = tid & 63;
  const int q = lane >> 4, lr = lane & 15;
  const int base = chunk * CHUNK;

  // stage Wi_b slice once: row r = gate*24 + n  <-  WiTb[gate*768 + j0 + n][0..512)
  for (int c = tid; c < 96 * 64; c += 256) {
    const int r = c >> 6, k8 = c & 63;
    const int gate = r / SLW, n = r % SLW;
    *(float4*)(wlds + (size_t)r * EROW + k8 * 8) =
        *(const float4*)(WiTb + (size_t)(gate * H_DIM + j0 + n) * E_DIM + k8 * 8);
  }

  // scan ownership (tid<128): (row, col0..col0+2)
  const int row = tid >> 3, wloc = tid & 7, col0 = 3 * wloc;
  float hw0[3], hw1[3], hw2[3], hw3[3], c2r[3] = {0.f, 0.f, 0.f};
  if (tid < 128) {
    const int b = r0 + row;
    #pragma unroll
    for (int j = 0; j < 3; ++j) {
      const int n = j0 + col0 + j;
      hw0[j] = BiasB[n]        + hTW[(size_t)b * G4 + n];
      hw1[j] = BiasB[768 + n]  + hTW[(size_t)b * G4 + 768 + n];
      hw2[j] = BiasB[1536 + n] + hTW[(size_t)b * G4 + 1536 + n];
      hw3[j] = BiasB[2304 + n] + hTW[(size_t)b * G4 + 2304 + n];
      c2r[j] = c2state[(size_t)b * H_DIM + n];
    }
  }
  const int wn0 = lr;                  // n-tile 0: cols 0..15
  const int wn1 = 16 + (lr & 7);       // n-tile 1: cols 16..23 (lanes lr>=8 duplicate)
  const unsigned short* wb0 = wlds + (size_t)(w * SLW + wn0) * EROW;
  const unsigned short* wb1 = wlds + (size_t)(w * SLW + wn1) * EROW;
  __syncthreads();

  for (int t = CHUNK / 2 - 1; t >= 0; --t) {   // 2-step groups, descending
    // ---- stage emb rows: a<16 -> step 2t+1, a>=16 -> step 2t ----
    for (int c = tid; c < 32 * 64; c += 256) {
      const int a = c >> 6, k8 = c & 63;
      const int ss = 2 * t + 1 - (a >> 4);
      *(float4*)(&emb_s[a][k8 * 8]) =
          *(const float4*)(Emb + ((size_t)(base + ss) * B_DIM + r0 + (a & 15)) * E_DIM + k8 * 8);
    }
    __syncthreads();   // B1: emb staged (also orders prev-iter g_lds reads before rewrite)

    // ---- GEMM: gate w, [32 rows x 512 k x 24 cols] ----
    f32x4 a00 = {0.f,0.f,0.f,0.f}, a01 = {0.f,0.f,0.f,0.f};
    f32x4 a10 = {0.f,0.f,0.f,0.f}, a11 = {0.f,0.f,0.f,0.f};
    #pragma unroll
    for (int kt = 0; kt < 16; ++kt) {
      const int ko = kt * 32 + q * 8;
      const bf16x8 b0 = *(const bf16x8*)(wb0 + ko);
      const bf16x8 b1 = *(const bf16x8*)(wb1 + ko);
      const bf16x8 aA = *(const bf16x8*)(&emb_s[lr][ko]);
      const bf16x8 aB = *(const bf16x8*)(&emb_s[16 + lr][ko]);
      a00 = __builtin_amdgcn_mfma_f32_16x16x32_bf16(aA, b0, a00, 0, 0, 0);
      a01 = __builtin_amdgcn_mfma_f32_16x16x32_bf16(aA, b1, a01, 0, 0, 0);
      a10 = __builtin_amdgcn_mfma_f32_16x16x32_bf16(aB, b0, a10, 0, 0, 0);
      a11 = __builtin_amdgcn_mfma_f32_16x16x32_bf16(aB, b1, a11, 0, 0, 0);
    }
    #pragma unroll
    for (int i = 0; i < 4; ++i) {
      g_lds[w][0][q * 4 + i][lr] = a00[i];
      g_lds[w][1][q * 4 + i][lr] = a10[i];
    }
    if (lr < 8) {
      #pragma unroll
      for (int i = 0; i < 4; ++i) {
        g_lds[w][0][q * 4 + i][16 + lr] = a01[i];
        g_lds[w][1][q * 4 + i][16 + lr] = a11[i];
      }
    }
    __syncthreads();   // B2: gates ready

    // ---- scan: step 2t+1 (st=0) then 2t (st=1), descending ----
    if (tid < 128) {
      #pragma unroll
      for (int st = 0; st < 2; ++st) {
        const int gs = base + 2 * t + 1 - st;
        unsigned short hb[3];
        #pragma unroll
        for (int j = 0; j < 3; ++j) {
          const float rv = sigmf_(g_lds[0][st][row][col0 + j] + hw0[j]);
          const float fv = sigmf_(g_lds[1][st][row][col0 + j] + hw1[j]);
          const float gv = tanhf2(g_lds[2][st][row][col0 + j] + hw2[j]);
          const float ov = sigmf_(g_lds[3][st][row][col0 + j] + hw3[j]);
          c2r[j] = fv * c2r[j] + rv * gv;
          hb[j] = packbf(ov * tanhf2(c2r[j]));
        }
        unsigned short* hsp = (unsigned short*)(Hs + ((size_t)gs * B_DIM + r0 + row) * H2
                                                + H_DIM + j0 + col0);
        hsp[0] = hb[0]; hsp[1] = hb[1]; hsp[2] = hb[2];
      }
    }
    // no trailing barrier: next B1 orders g_lds reuse; emb_s disjoint from scan
  }

  if (tid < 128) {
    #pragma unroll
    for (int j = 0; j < 3; ++j)
      c2state[(size_t)(r0 + row) * H_DIM + j0 + col0 + j] = c2r[j];
  }
}

// ---------------- standalone backward scan over materialized X (fallback) ----------------
__global__ __launch_bounds__(256) void k_bwd_scan(const __hip_bfloat16* __restrict__ X,
                                                  const float* __restrict__ hTW,
                                                  __hip_bfloat16* __restrict__ Hs,
                                                  float* __restrict__ c2state,
                                                  int chunk) {
  const int t = blockIdx.x * 256 + threadIdx.x;    // 49152
  const int b = t / H_DIM;
  const int j = t % H_DIM;
  const int base = chunk * CHUNK;
  const float hw0 = hTW[(size_t)b * G4 + j];
  const float hw1 = hTW[(size_t)b * G4 + 768 + j];
  const float hw2 = hTW[(size_t)b * G4 + 1536 + j];
  const float hw3 = hTW[(size_t)b * G4 + 2304 + j];
  float c2 = c2state[t];
  for (int s = CHUNK - 1; s >= 0; --s) {
    const size_t xb = ((size_t)s * B_DIM + b) * G4 + j;
    const float r = sigmf_(__bfloat162float(X[xb]) + hw0);
    const float f = sigmf_(__bfloat162float(X[xb + 768]) + hw1);
    const float g = tanhf2(__bfloat162float(X[xb + 1536]) + hw2);
    const float o = sigmf_(__bfloat162float(X[xb + 2304]) + hw3);
    c2 = f * c2 + r * g;
    Hs[((size_t)(base + s) * B_DIM + b) * H2 + H_DIM + j] = __float2bfloat16(o * tanhf2(c2));
  }
  c2state[t] = c2;
}

// ---------------- host launcher ----------------
extern "C" void kernel_launch(void* const* d_in, const int* in_sizes, int n_in,
                              void* d_out, int out_size, void* d_ws, size_t ws_size,
                              hipStream_t stream) {
  const int*   tokens = (const int*)d_in[0];
  const float* emb    = (const float*)d_in[2];
  const float* Wi_f   = (const float*)d_in[3];
  const float* bi_f   = (const float*)d_in[4];
  const float* Wh_f   = (const float*)d_in[5];
  const float* bh_f   = (const float*)d_in[6];
  const float* Wi_b   = (const float*)d_in[7];
  const float* bi_b   = (const float*)d_in[8];
  const float* Wh_b   = (const float*)d_in[9];
  const float* bh_b   = (const float*)d_in[10];
  const float* Wout   = (const float*)d_in[11];
  const float* bout   = (const float*)d_in[12];
  float* out = (float*)d_out;
  char* ws = (char*)d_ws;

  size_t off = 0;
  auto alloc = [&](size_t bytes) { size_t o = off; off += (bytes + 255) & ~(size_t)255; return o; };
  const size_t oHs    = alloc((size_t)M_ROWS * H2 * 2);        // 100.7 MB
  const size_t oX0    = alloc((size_t)CM * G4 * 2);            // 50.3 MB
  const size_t oWhTf  = alloc((size_t)G4 * H_DIM * 2);         // 4.7 MB
  const size_t oWiTf  = alloc((size_t)G4 * E_DIM * 2);         // 3.1 MB
  const size_t oWiTb  = alloc((size_t)G4 * E_DIM * 2);         // 3.1 MB
  const size_t oBiasF = alloc((size_t)G4 * 4);
  const size_t oBiasB = alloc((size_t)G4 * 4);
  const size_t oHbuf  = alloc((size_t)2 * PSTR * 8);           // 256 KB packed h
  const size_t oCst   = alloc((size_t)B_DIM * H_DIM * 4);
  const size_t oHT    = alloc((size_t)B_DIM * H_DIM * 4);
  const size_t oHTW   = alloc((size_t)B_DIM * G4 * 4);
  const size_t oC2    = alloc((size_t)B_DIM * H_DIM * 4);
  const size_t oX1    = alloc((size_t)CM * G4 * 2);            // 50.3 MB (overlap only)
  const bool overlap = (off <= ws_size);                       // ~214 MB
  const size_t oEmb   = alloc((size_t)M_ROWS * E_DIM * 2);     // 33.6 MB (tier A only)
  const bool tierA = (off <= ws_size);                         // ~248 MB
  (void)in_sizes; (void)n_in; (void)out_size;

  __hip_bfloat16* Hs   = (__hip_bfloat16*)(ws + oHs);
  __hip_bfloat16* X0   = (__hip_bfloat16*)(ws + oX0);
  __hip_bfloat16* X1   = overlap ? (__hip_bfloat16*)(ws + oX1) : X0;
  __hip_bfloat16* Emb  = tierA ? (__hip_bfloat16*)(ws + oEmb) : (__hip_bfloat16*)nullptr;
  __hip_bfloat16* WhTf = (__hip_bfloat16*)(ws + oWhTf);
  __hip_bfloat16* WiTf = (__hip_bfloat16*)(ws + oWiTf);
  __hip_bfloat16* WiTb = (__hip_bfloat16*)(ws + oWiTb);
  float*          BiasF= (float*)(ws + oBiasF);
  float*          BiasB= (float*)(ws + oBiasB);
  ull_t*          Hbuf = (ull_t*)(ws + oHbuf);
  float*          Cst  = (float*)(ws + oCst);
  float*          HT   = (float*)(ws + oHT);
  float*          HTW  = (float*)(ws + oHTW);
  float*          C2   = (float*)(ws + oC2);

  hipMemsetAsync(ws + oHbuf, 0, (size_t)2 * PSTR * 8, stream);   // h_0 = 0, tag 0
  hipMemsetAsync(ws + oCst, 0, (size_t)B_DIM * H_DIM * 4, stream);
  hipMemsetAsync(ws + oC2, 0, (size_t)B_DIM * H_DIM * 4, stream);

  if (tierA)
    k_gather<<<8192, 256, 0, stream>>>(tokens, emb, Emb);
  k_transpose_cast<<<dim3(96, 24), 256, 0, stream>>>(Wh_f, WhTf, 768, 3072);
  k_transpose_cast<<<dim3(96, 16), 256, 0, stream>>>(Wi_f, WiTf, 512, 3072);
  k_transpose_cast<<<dim3(96, 16), 256, 0, stream>>>(Wi_b, WiTb, 512, 3072);
  k_bias<<<12, 256, 0, stream>>>(bi_f, bh_f, BiasF);
  k_bias<<<12, 256, 0, stream>>>(bi_b, bh_b, BiasB);

  if (overlap && tierA) {
    // prologue: X chunk 0 (forward)
    k_gemm_e<<<NTILES, 256, 0, stream>>>(Emb, WiTf, BiasF, X0);
    auto EA = [&](int c) { return Emb + (size_t)c * CM * E_DIM; };
    // forward: scan(c) || X-GEMM(next); fwd c reads buf[c&1]. chunk 3: scan only.
    k_fwd_fused<<<240, 256, 0, stream>>>(X0, WhTf, Hbuf, Hs, Cst, HT, 0,
                                         EA(1), tokens, emb, WiTf, BiasF, X1);
    k_fwd_fused<<<240, 256, 0, stream>>>(X1, WhTf, Hbuf, Hs, Cst, HT, 1,
                                         EA(2), tokens, emb, WiTf, BiasF, X0);
    k_fwd_fused<<<240, 256, 0, stream>>>(X0, WhTf, Hbuf, Hs, Cst, HT, 2,
                                         EA(3), tokens, emb, WiTf, BiasF, X1);
    k_fwd_fused<<<128, 256, 0, stream>>>(X1, WhTf, Hbuf, Hs, Cst, HT, 3,
                                         EA(0), tokens, emb, WiTf, BiasF, X0);
    k_hTW<<<dim3(12, 64), 256, 0, stream>>>(HT, Wh_b, HTW);
    // backward: fused GEMM+scan (no X); out workers trail by one chunk.
    k_bwd_fused2<<<256, 256, 0, stream>>>(Emb, WiTb, BiasB, HTW, Hs, C2, 3, -1,
                                          Wout, bout, tokens, out);
    k_bwd_fused2<<<256, 256, 0, stream>>>(Emb, WiTb, BiasB, HTW, Hs, C2, 2, 3,
                                          Wout, bout, tokens, out);
    k_bwd_fused2<<<256, 256, 0, stream>>>(Emb, WiTb, BiasB, HTW, Hs, C2, 1, 2,
                                          Wout, bout, tokens, out);
    k_bwd_fused2<<<256, 256, 0, stream>>>(Emb, WiTb, BiasB, HTW, Hs, C2, 0, 1,
                                          Wout, bout, tokens, out);
    k_out<<<1024, 256, 0, stream>>>(Hs, Wout, bout, tokens, out);   // chunk 0
  } else if (overlap) {
    // Tier B: forward fused with gather workers; backward via materialized X (R4-style)
    k_gemm_g<<<NTILES, 256, 0, stream>>>(tokens, emb, WiTf, BiasF, X0);
    k_fwd_fused<<<240, 256, 0, stream>>>(X0, WhTf, Hbuf, Hs, Cst, HT, 0,
                                         nullptr, tokens + 1 * CM, emb, WiTf, BiasF, X1);
    k_fwd_fused<<<240, 256, 0, stream>>>(X1, WhTf, Hbuf, Hs, Cst, HT, 1,
                                         nullptr, tokens + 2 * CM, emb, WiTf, BiasF, X0);
    k_fwd_fused<<<240, 256, 0, stream>>>(X0, WhTf, Hbuf, Hs, Cst, HT, 2,
                                         nullptr, tokens + 3 * CM, emb, WiTf, BiasF, X1);
    k_fwd_fused<<<240, 256, 0, stream>>>(X1, WhTf, Hbuf, Hs, Cst, HT, 3,
                                         nullptr, tokens + 3 * CM, emb, WiTb, BiasB, X0);
    k_hTW<<<dim3(12, 64), 256, 0, stream>>>(HT, Wh_b, HTW);
    k_bwd_scan<<<192, 256, 0, stream>>>(X0, HTW, Hs, C2, 3);
    for (int c = 2; c >= 0; --c) {
      k_gemm_g<<<NTILES, 256, 0, stream>>>(tokens + (size_t)c * CM, emb, WiTb, BiasB, X1);
      k_bwd_scan<<<192, 256, 0, stream>>>(X1, HTW, Hs, C2, c);
    }
    k_out<<<4096, 256, 0, stream>>>(Hs, Wout, bout, tokens, out);
  } else {
    // sequential fallback (single X buffer, gather-fused)
    for (int c = 0; c < 4; ++c) {
      k_gemm_g<<<NTILES, 256, 0, stream>>>(tokens + (size_t)c * CM, emb, WiTf, BiasF, X0);
      k_fwd_fused<<<128, 256, 0, stream>>>(X0, WhTf, Hbuf, Hs, Cst, HT, c,
                                           nullptr, tokens, emb, WiTf, BiasF, X0);
    }
    k_hTW<<<dim3(12, 64), 256, 0, stream>>>(HT, Wh_b, HTW);
    for (int c = 3; c >= 0; --c) {
      k_gemm_g<<<NTILES, 256, 0, stream>>>(tokens + (size_t)c * CM, emb, WiTb, BiasB, X0);
      k_bwd_scan<<<192, 256, 0, stream>>>(X0, HTW, Hs, C2, c);
    }
    k_out<<<4096, 256, 0, stream>>>(Hs, Wout, bout, tokens, out);
  }
}

// Round 9
// 3135.024 us; speedup vs baseline: 1.1463x; 1.1463x over previous
//
#include <hip/hip_runtime.h>
#include <hip/hip_bf16.h>
#include <stdint.h>

typedef __attribute__((ext_vector_type(8))) short bf16x8;
typedef __attribute__((ext_vector_type(4))) float f32x4;
typedef __attribute__((ext_vector_type(4))) unsigned int u32x4;
typedef unsigned long long ull_t;

#define S_LEN 512
#define B_DIM 64
#define E_DIM 512
#define H_DIM 768
#define G4    3072      // 4H (one direction's gate width)
#define H2    1536      // 2H (combined hs row)
#define M_ROWS 32768    // S*B
#define CHUNK 128       // seq steps per X-chunk
#define CM    8192      // CHUNK*B rows per chunk
#define SLW   24        // cols per slice
#define WPS   8         // published words per slice per row
#define WPR   256       // packed words per h row (256*3 = 768 cols)
#define RWRD  4096      // words per ring per parity (16 rows * 256)
#define PSTR  16384     // words per parity (4 rings)
#define KRES  640       // K columns resident in LDS (fwd scan)
#define KREG  4         // K-tail tiles in registers (fwd scan)
#define WROW  648       // padded LDS weight row, fwd (shorts)
#define NTILES 1536     // X-GEMM tiles per chunk (64 m x 24 n)
#define EROW  520       // padded 512-k row (shorts) for bwd fused GEMM

__device__ __forceinline__ float sigmf_(float x) { return 1.0f / (1.0f + __expf(-x)); }
__device__ __forceinline__ float tanhf2(float x) {
  x = fminf(fmaxf(x, -20.0f), 20.0f);
  float e = __expf(2.0f * x);
  return (e - 1.0f) / (e + 1.0f);
}
__device__ __forceinline__ float bfu(unsigned short u) { return __uint_as_float((unsigned)u << 16); }
__device__ __forceinline__ unsigned short packbf(float a) {
  __hip_bfloat16 t = __float2bfloat16(a);
  unsigned short b;
  __builtin_memcpy(&b, &t, 2);
  return b;
}

// ---------------- embedding gather + cast to bf16 ----------------
__global__ __launch_bounds__(256) void k_gather(const int* __restrict__ tokens,
                                                const float* __restrict__ emb,
                                                __hip_bfloat16* __restrict__ out) {
  const int t = blockIdx.x * 256 + threadIdx.x;
  const int e0 = t * 8;
  const int row = e0 >> 9;
  const int k = e0 & 511;
  const int tok = tokens[row];
  const float4* p = (const float4*)(emb + (size_t)tok * E_DIM + k);
  const float4 v0 = p[0], v1 = p[1];
  __align__(16) __hip_bfloat16 tmp[8];
  tmp[0] = __float2bfloat16(v0.x); tmp[1] = __float2bfloat16(v0.y);
  tmp[2] = __float2bfloat16(v0.z); tmp[3] = __float2bfloat16(v0.w);
  tmp[4] = __float2bfloat16(v1.x); tmp[5] = __float2bfloat16(v1.y);
  tmp[6] = __float2bfloat16(v1.z); tmp[7] = __float2bfloat16(v1.w);
  *(bf16x8*)(out + (size_t)t * 8) = *(const bf16x8*)tmp;
}

// ---------------- fp32 -> bf16 transpose (LDS tiled): dst[c*Rs+r]=src[r*Cs+c] ----------------
__global__ __launch_bounds__(256) void k_transpose_cast(const float* __restrict__ src,
                                                        __hip_bfloat16* __restrict__ dst,
                                                        int Rs, int Cs) {
  __shared__ float tile[32][33];
  const int tx = threadIdx.x & 31, ty = threadIdx.x >> 5;
  const int c0 = blockIdx.x * 32, r0 = blockIdx.y * 32;
  #pragma unroll
  for (int i = ty; i < 32; i += 8)
    tile[i][tx] = src[(size_t)(r0 + i) * Cs + c0 + tx];
  __syncthreads();
  #pragma unroll
  for (int i = ty; i < 32; i += 8)
    dst[(size_t)(c0 + i) * Rs + r0 + tx] = __float2bfloat16(tile[tx][i]);
}

// ---------------- combined bias for one direction: bi + bh ----------------
__global__ __launch_bounds__(256) void k_bias(const float* __restrict__ bi,
                                              const float* __restrict__ bh,
                                              float* __restrict__ bias) {
  const int n = blockIdx.x * 256 + threadIdx.x;
  bias[n] = bi[n] + bh[n];
}

// ---------------- X-GEMM tile, pre-gathered bf16 A (fast path) --------
__device__ __forceinline__ void gemm_tile_e(char* pool, int tile,
                                            const __hip_bfloat16* __restrict__ A,
                                            const __hip_bfloat16* __restrict__ BT,
                                            const float* __restrict__ bias,
                                            __hip_bfloat16* __restrict__ C) {
  auto As = (__hip_bfloat16 (*)[40])pool;
  auto Bs = (__hip_bfloat16 (*)[40])(pool + 10240);
  const int tid = threadIdx.x;
  const int wave = tid >> 6, lane = tid & 63;
  const int q = lane >> 4, lr = lane & 15;
  const int wm = (wave >> 1) * 64, wn = (wave & 1) * 64;
  const int nb = tile % 24, mb = tile / 24;
  const int m0 = mb * 128, n0 = nb * 128;
  const int srow = tid >> 2, skseg = (tid & 3) * 8;

  f32x4 acc[4][4];
  #pragma unroll
  for (int i = 0; i < 4; ++i)
    #pragma unroll
    for (int j = 0; j < 4; ++j) { f32x4 z = {0.f, 0.f, 0.f, 0.f}; acc[i][j] = z; }

  for (int kt = 0; kt < 16; ++kt) {
    __syncthreads();
    const int kbase = kt * 32 + skseg;
    *(bf16x8*)&As[srow][skseg]      = *(const bf16x8*)(A + (size_t)(m0 + srow) * E_DIM + kbase);
    *(bf16x8*)&As[srow + 64][skseg] = *(const bf16x8*)(A + (size_t)(m0 + srow + 64) * E_DIM + kbase);
    *(bf16x8*)&Bs[srow][skseg]      = *(const bf16x8*)(BT + (size_t)(n0 + srow) * E_DIM + kbase);
    *(bf16x8*)&Bs[srow + 64][skseg] = *(const bf16x8*)(BT + (size_t)(n0 + srow + 64) * E_DIM + kbase);
    __syncthreads();
    bf16x8 af[4], bfr[4];
    #pragma unroll
    for (int mt = 0; mt < 4; ++mt) af[mt] = *(const bf16x8*)&As[wm + mt * 16 + lr][q * 8];
    #pragma unroll
    for (int nt = 0; nt < 4; ++nt) bfr[nt] = *(const bf16x8*)&Bs[wn + nt * 16 + lr][q * 8];
    #pragma unroll
    for (int mt = 0; mt < 4; ++mt)
      #pragma unroll
      for (int nt = 0; nt < 4; ++nt)
        acc[mt][nt] = __builtin_amdgcn_mfma_f32_16x16x32_bf16(af[mt], bfr[nt], acc[mt][nt], 0, 0, 0);
  }
  #pragma unroll
  for (int mt = 0; mt < 4; ++mt) {
    #pragma unroll
    for (int nt = 0; nt < 4; ++nt) {
      const int col = n0 + wn + nt * 16 + lr;
      const float bv = bias[col];
      #pragma unroll
      for (int i = 0; i < 4; ++i) {
        const int row = m0 + wm + mt * 16 + q * 4 + i;
        C[(size_t)row * G4 + col] = __float2bfloat16(acc[mt][nt][i] + bv);
      }
    }
  }
}

// ---------------- X-GEMM tile with fused embedding gather (fallback tiers) ----------------
__device__ __forceinline__ void gemm_tile_g(char* pool, int tile,
                                            const int* __restrict__ tokens_c,
                                            const float* __restrict__ emb,
                                            const __hip_bfloat16* __restrict__ BT,
                                            const float* __restrict__ bias,
                                            __hip_bfloat16* __restrict__ C) {
  auto As = (__hip_bfloat16 (*)[40])pool;
  auto Bs = (__hip_bfloat16 (*)[40])(pool + 10240);
  const int tid = threadIdx.x;
  const int wave = tid >> 6, lane = tid & 63;
  const int q = lane >> 4, lr = lane & 15;
  const int wm = (wave >> 1) * 64, wn = (wave & 1) * 64;
  const int nb = tile % 24, mb = tile / 24;
  const int m0 = mb * 128, n0 = nb * 128;
  const int srow = tid >> 2, skseg = (tid & 3) * 8;
  const int tok0 = tokens_c[m0 + srow];
  const int tok1 = tokens_c[m0 + srow + 64];

  f32x4 acc[4][4];
  #pragma unroll
  for (int i = 0; i < 4; ++i)
    #pragma unroll
    for (int j = 0; j < 4; ++j) { f32x4 z = {0.f, 0.f, 0.f, 0.f}; acc[i][j] = z; }

  for (int kt = 0; kt < 16; ++kt) {
    __syncthreads();
    const int kbase = kt * 32 + skseg;
    {
      const float* ap = emb + (size_t)tok0 * E_DIM + kbase;
      const float4 v0 = *(const float4*)ap, v1 = *(const float4*)(ap + 4);
      __align__(16) __hip_bfloat16 t8[8];
      t8[0] = __float2bfloat16(v0.x); t8[1] = __float2bfloat16(v0.y);
      t8[2] = __float2bfloat16(v0.z); t8[3] = __float2bfloat16(v0.w);
      t8[4] = __float2bfloat16(v1.x); t8[5] = __float2bfloat16(v1.y);
      t8[6] = __float2bfloat16(v1.z); t8[7] = __float2bfloat16(v1.w);
      *(bf16x8*)&As[srow][skseg] = *(const bf16x8*)t8;
    }
    {
      const float* ap = emb + (size_t)tok1 * E_DIM + kbase;
      const float4 v0 = *(const float4*)ap, v1 = *(const float4*)(ap + 4);
      __align__(16) __hip_bfloat16 t8[8];
      t8[0] = __float2bfloat16(v0.x); t8[1] = __float2bfloat16(v0.y);
      t8[2] = __float2bfloat16(v0.z); t8[3] = __float2bfloat16(v0.w);
      t8[4] = __float2bfloat16(v1.x); t8[5] = __float2bfloat16(v1.y);
      t8[6] = __float2bfloat16(v1.z); t8[7] = __float2bfloat16(v1.w);
      *(bf16x8*)&As[srow + 64][skseg] = *(const bf16x8*)t8;
    }
    *(bf16x8*)&Bs[srow][skseg]      = *(const bf16x8*)(BT + (size_t)(n0 + srow) * E_DIM + kbase);
    *(bf16x8*)&Bs[srow + 64][skseg] = *(const bf16x8*)(BT + (size_t)(n0 + srow + 64) * E_DIM + kbase);
    __syncthreads();
    bf16x8 af[4], bfr[4];
    #pragma unroll
    for (int mt = 0; mt < 4; ++mt) af[mt] = *(const bf16x8*)&As[wm + mt * 16 + lr][q * 8];
    #pragma unroll
    for (int nt = 0; nt < 4; ++nt) bfr[nt] = *(const bf16x8*)&Bs[wn + nt * 16 + lr][q * 8];
    #pragma unroll
    for (int mt = 0; mt < 4; ++mt)
      #pragma unroll
      for (int nt = 0; nt < 4; ++nt)
        acc[mt][nt] = __builtin_amdgcn_mfma_f32_16x16x32_bf16(af[mt], bfr[nt], acc[mt][nt], 0, 0, 0);
  }
  #pragma unroll
  for (int mt = 0; mt < 4; ++mt) {
    #pragma unroll
    for (int nt = 0; nt < 4; ++nt) {
      const int col = n0 + wn + nt * 16 + lr;
      const float bv = bias[col];
      #pragma unroll
      for (int i = 0; i < 4; ++i) {
        const int row = m0 + wm + mt * 16 + q * 4 + i;
        C[(size_t)row * G4 + col] = __float2bfloat16(acc[mt][nt][i] + bv);
      }
    }
  }
}

// ---------------- standalone X-GEMMs ----------------
__global__ __launch_bounds__(256) void k_gemm_e(const __hip_bfloat16* __restrict__ A,
                                                const __hip_bfloat16* __restrict__ BT,
                                                const float* __restrict__ bias,
                                                __hip_bfloat16* __restrict__ C) {
  __shared__ __align__(16) char pool[20480];
  gemm_tile_e(pool, blockIdx.x, A, BT, bias, C);
}
__global__ __launch_bounds__(256) void k_gemm_g(const int* __restrict__ tokens_c,
                                                const float* __restrict__ emb,
                                                const __hip_bfloat16* __restrict__ BT,
                                                const float* __restrict__ bias,
                                                __hip_bfloat16* __restrict__ C) {
  __shared__ __align__(16) char pool[20480];
  gemm_tile_g(pool, blockIdx.x, tokens_c, emb, BT, bias, C);
}

// ---------------- output block of 8 rows ----------------
__device__ __forceinline__ void out_block8(char* pool, int ob,
                                           const __hip_bfloat16* __restrict__ Hs,
                                           const float* __restrict__ Wout,
                                           const float* __restrict__ bout,
                                           const int* __restrict__ tokens,
                                           float* __restrict__ out) {
  auto rowbuf = (float (*)[1536])pool;
  const int r0 = ob * 8;
  const int tid = threadIdx.x;
  for (int idx = tid; idx < 8 * 1536; idx += 256) {
    const int rr = idx / 1536, k = idx % 1536;
    rowbuf[rr][k] = __bfloat162float(Hs[(size_t)(r0 + rr) * H2 + k]);
  }
  __syncthreads();
  const int l = tid & 31, rr = tid >> 5;
  float acc = bout[l];
  #pragma unroll 8
  for (int k = 0; k < 1536; ++k) acc += rowbuf[rr][k] * Wout[k * 32 + l];
  const int row = r0 + rr;
  if (l == 0 && tokens[row] == 1) acc += 10000.0f;
  out[(size_t)row * 32 + l] = acc;
  __syncthreads();   // rowbuf reused by next iteration
}

__global__ __launch_bounds__(256) void k_out(const __hip_bfloat16* __restrict__ Hs,
                                             const float* __restrict__ Wout,
                                             const float* __restrict__ bout,
                                             const int* __restrict__ tokens,
                                             float* __restrict__ out) {
  __shared__ __align__(16) char pool[49152];
  out_block8(pool, blockIdx.x, Hs, Wout, bout, tokens, out);
}

// ---------------- forward scan (+ co-scheduled next-chunk X-GEMM workers) ----------------
__global__ __launch_bounds__(256, 1) void k_fwd_fused(const __hip_bfloat16* __restrict__ X,
                                                      const __hip_bfloat16* __restrict__ WhTf,
                                                      ull_t* __restrict__ hbuf,
                                                      __hip_bfloat16* __restrict__ Hs,
                                                      float* __restrict__ cstate,
                                                      float* __restrict__ hT,
                                                      int chunk,
                                                      const __hip_bfloat16* __restrict__ EmbA,
                                                      const int* __restrict__ tokens_nx,
                                                      const float* __restrict__ emb,
                                                      const __hip_bfloat16* __restrict__ WiT_nx,
                                                      const float* __restrict__ Bias_nx,
                                                      __hip_bfloat16* __restrict__ Xw) {
  __shared__ __align__(16) char pool[155904];
  const int bx = blockIdx.x;

  if (bx >= 128) {                       // ---- GEMM worker role ----
    const int nw = gridDim.x - 128;
    if (EmbA) {
      for (int t = bx - 128; t < NTILES; t += nw)
        gemm_tile_e(pool, t, EmbA, WiT_nx, Bias_nx, Xw);
    } else {
      for (int t = bx - 128; t < NTILES; t += nw)
        gemm_tile_g(pool, t, tokens_nx, emb, WiT_nx, Bias_nx, Xw);
    }
    return;
  }

  // ---- scan role: identical to the verified R4 kernel ----
  unsigned short* wlds = (unsigned short*)pool;                       // 124,416 B
  auto h_stage = (unsigned short (*)[776])(pool + 124416);            //  24,832 B
  auto g_lds   = (float (*)[16][26])(pool + 149248);                  //   6,656 B

  const int group = bx >> 5;
  const int slice = bx & 31;
  const int r0 = group * 16;
  const int j0 = slice * SLW;
  const int tid = threadIdx.x;
  const int w = tid >> 6;
  const int lane = tid & 63;
  const int q = lane >> 4, lr = lane & 15;
  const int base = chunk * CHUNK;

  const int prow = tid >> 4;
  const int pw   = tid & 15;

  const int row  = tid >> 3;
  const int wloc = tid & 7;
  const int col0 = 3 * wloc;

  for (int c = tid; c < 96 * (KRES / 8); c += 256) {
    const int r = c / (KRES / 8), k8 = c % (KRES / 8);
    const int gate = r / SLW, n = r % SLW;
    const float4 v = *(const float4*)(WhTf + (size_t)(gate * H_DIM + j0 + n) * H_DIM + k8 * 8);
    *(float4*)(wlds + (size_t)r * WROW + k8 * 8) = v;
  }

  const int wn0 = lr;
  const int wn1 = 16 + (lr & 7);
  bf16x8 wr0[KREG], wr1[KREG];
  #pragma unroll
  for (int kk = 0; kk < KREG; ++kk) {
    const int ko = KRES + kk * 32 + q * 8;
    wr0[kk] = *(const bf16x8*)(WhTf + (size_t)(w * H_DIM + j0 + wn0) * H_DIM + ko);
    wr1[kk] = *(const bf16x8*)(WhTf + (size_t)(w * H_DIM + j0 + wn1) * H_DIM + ko);
  }

  float cr[3] = {0.f, 0.f, 0.f};
  if (tid < 128) {
    const float* cs = cstate + (size_t)(r0 + row) * H_DIM + j0 + col0;
    cr[0] = cs[0]; cr[1] = cs[1]; cr[2] = cs[2];
  }

  const unsigned skipbit = ((pw >> 2) == (slice & 3)) ? (1u << (slice >> 2)) : 0u;

  __syncthreads();

  for (int s = 0; s < CHUNK; ++s) {
    const int gs = base + s;

    unsigned short xs[4][3];
    if (tid < 128) {
      const unsigned short* xp = (const unsigned short*)(X + ((size_t)s * B_DIM + r0 + row) * G4 + j0 + col0);
      #pragma unroll
      for (int g = 0; g < 4; ++g)
        #pragma unroll
        for (int j = 0; j < 3; ++j) xs[g][j] = xp[g * H_DIM + j];
    }

    const ull_t* hc = hbuf + ((size_t)(gs & 1)) * PSTR + (size_t)group * RWRD
                    + (size_t)prow * WPR + 2 * pw;
    u32x4 d0 = {0,0,0,0}, d1 = {0,0,0,0}, d2 = {0,0,0,0}, d3 = {0,0,0,0};
    u32x4 d4 = {0,0,0,0}, d5 = {0,0,0,0}, d6 = {0,0,0,0}, d7 = {0,0,0,0};
    const unsigned pollmask = (s == 0) ? 0xFFu : (0xFFu ^ skipbit);
    {
      const unsigned e16 = (unsigned)(unsigned short)gs;
      unsigned need = pollmask;
      long guard = 0;
      for (;;) {
#define POLL_LD(i, dv) \
        if (need & (1u << (i))) \
          asm volatile("global_load_dwordx4 %0, %1, off sc0 sc1" \
                       : "=v"(dv) : "v"(hc + 32 * (i)) : "memory");
        POLL_LD(0, d0) POLL_LD(1, d1) POLL_LD(2, d2) POLL_LD(3, d3)
        POLL_LD(4, d4) POLL_LD(5, d5) POLL_LD(6, d6) POLL_LD(7, d7)
#undef POLL_LD
        asm volatile("s_waitcnt vmcnt(0)"
                     : "+v"(d0), "+v"(d1), "+v"(d2), "+v"(d3),
                       "+v"(d4), "+v"(d5), "+v"(d6), "+v"(d7)
                     :: "memory");
        unsigned nn = 0;
#define POLL_CK(i, dv) \
        if ((need & (1u << (i))) && \
            ((((dv).x & 0xFFFFu) != e16) || (((dv).z & 0xFFFFu) != e16))) nn |= 1u << (i);
        POLL_CK(0, d0) POLL_CK(1, d1) POLL_CK(2, d2) POLL_CK(3, d3)
        POLL_CK(4, d4) POLL_CK(5, d5) POLL_CK(6, d6) POLL_CK(7, d7)
#undef POLL_CK
        need = nn;
        if (!need) break;
        if (++guard > (1L << 20)) break;
        __builtin_amdgcn_s_sleep(1);
      }
    }
    {
#define STAGE_PAIR(i, dv) \
      if (pollmask & (1u << (i))) { \
        unsigned* hp = (unsigned*)&h_stage[prow][6 * pw + 96 * (i)]; \
        hp[0] = ((dv).x >> 16) | ((dv).y << 16); \
        hp[1] = ((dv).y >> 16) | ((dv).z & 0xFFFF0000u); \
        hp[2] = (dv).w; \
      }
      STAGE_PAIR(0, d0) STAGE_PAIR(1, d1) STAGE_PAIR(2, d2) STAGE_PAIR(3, d3)
      STAGE_PAIR(4, d4) STAGE_PAIR(5, d5) STAGE_PAIR(6, d6) STAGE_PAIR(7, d7)
#undef STAGE_PAIR
    }
    __syncthreads();   // B1: h staged

    f32x4 acc0 = {0.f, 0.f, 0.f, 0.f};
    f32x4 acc1 = {0.f, 0.f, 0.f, 0.f};
    {
      const unsigned short* wb = wlds + (size_t)w * SLW * WROW;
      #pragma unroll
      for (int kt = 0; kt < KRES / 32; ++kt) {
        const int ko = kt * 32 + q * 8;
        const bf16x8 a  = *(const bf16x8*)&h_stage[lr][ko];
        const bf16x8 b0 = *(const bf16x8*)(wb + (size_t)wn0 * WROW + ko);
        const bf16x8 b1 = *(const bf16x8*)(wb + (size_t)wn1 * WROW + ko);
        acc0 = __builtin_amdgcn_mfma_f32_16x16x32_bf16(a, b0, acc0, 0, 0, 0);
        acc1 = __builtin_amdgcn_mfma_f32_16x16x32_bf16(a, b1, acc1, 0, 0, 0);
      }
      #pragma unroll
      for (int kk = 0; kk < KREG; ++kk) {
        const bf16x8 a = *(const bf16x8*)&h_stage[lr][KRES + kk * 32 + q * 8];
        acc0 = __builtin_amdgcn_mfma_f32_16x16x32_bf16(a, wr0[kk], acc0, 0, 0, 0);
        acc1 = __builtin_amdgcn_mfma_f32_16x16x32_bf16(a, wr1[kk], acc1, 0, 0, 0);
      }
    }
    #pragma unroll
    for (int i = 0; i < 4; ++i) g_lds[w][q * 4 + i][lr] = acc0[i];
    if (lr < 8) {
      #pragma unroll
      for (int i = 0; i < 4; ++i) g_lds[w][q * 4 + i][16 + lr] = acc1[i];
    }
    __syncthreads();   // B2: gates ready

    if (tid < 128) {
      float h[3];
      #pragma unroll
      for (int j = 0; j < 3; ++j) {
        const float rv = g_lds[0][row][col0 + j] + bfu(xs[0][j]);
        const float fv = g_lds[1][row][col0 + j] + bfu(xs[1][j]);
        const float gv = g_lds[2][row][col0 + j] + bfu(xs[2][j]);
        const float ov = g_lds[3][row][col0 + j] + bfu(xs[3][j]);
        const float c = sigmf_(fv) * cr[j] + sigmf_(rv) * tanhf2(gv);
        cr[j] = c;
        h[j] = sigmf_(ov) * tanhf2(c);
      }
      const unsigned short b0 = packbf(h[0]), b1 = packbf(h[1]), b2 = packbf(h[2]);
      const ull_t wv = (ull_t)(unsigned short)(gs + 1)
                     | ((ull_t)b0 << 16) | ((ull_t)b1 << 32) | ((ull_t)b2 << 48);
      __hip_atomic_store(hbuf + ((size_t)((gs + 1) & 1)) * PSTR + (size_t)group * RWRD
                         + (size_t)row * WPR + slice * WPS + wloc,
                         wv, __ATOMIC_RELAXED, __HIP_MEMORY_SCOPE_AGENT);
      h_stage[row][j0 + col0]     = b0;
      h_stage[row][j0 + col0 + 1] = b1;
      h_stage[row][j0 + col0 + 2] = b2;
      unsigned short* hsp = (unsigned short*)(Hs + ((size_t)gs * B_DIM + r0 + row) * H2 + j0 + col0);
      hsp[0] = b0; hsp[1] = b1; hsp[2] = b2;
      if (chunk == 3 && s == CHUNK - 1) {
        float* hp = hT + (size_t)(r0 + row) * H_DIM + j0 + col0;
        hp[0] = h[0]; hp[1] = h[1]; hp[2] = h[2];
      }
    }
  }

  if (tid < 128) {
    float* cs = cstate + (size_t)(r0 + row) * H_DIM + j0 + col0;
    cs[0] = cr[0]; cs[1] = cr[1]; cs[2] = cr[2];
  }
}

// ---------------- hTW[b,n] = hT[b,:] @ Wh_b[:,n] ----------------
__global__ __launch_bounds__(256) void k_hTW(const float* __restrict__ hT,
                                             const float* __restrict__ Whb,
                                             float* __restrict__ hTW) {
  const int b = blockIdx.y;
  const int n = blockIdx.x * 256 + threadIdx.x;
  __shared__ float hs[768];
  for (int i = threadIdx.x; i < 768; i += 256) hs[i] = hT[b * 768 + i];
  __syncthreads();
  float acc = 0.f;
  #pragma unroll 4
  for (int k = 0; k < 768; ++k) acc += hs[k] * Whb[(size_t)k * G4 + n];
  hTW[(size_t)b * G4 + n] = acc;
}

// ---------------- fused backward v3: full-machine, software-pipelined ----------------
// 256 blocks = 8 batch-groups (8 rows) x 32 col-slices (24 cols). No X materialization.
// Per 2-step group (descending): write prefetched emb regs -> emb_s[buf] (double-
// buffered), ISSUE next group's global loads (latency hides under GEMM), B1, single-
// m-tile GEMM [16m x 512k x 24n] per gate-wave, B2, 64-thread scan (2 steps).
// R8's failure fixed: (a) all 256 CUs do GEMM (no out-worker role; k_out runs
// standalone), (b) staging latency pipelined instead of serialized.
// emb_s WAR safety: write at iter t; last read was GEMM at t-2 (same parity);
// B1(t-1) and B2(t-1) order them.
__global__ __launch_bounds__(256, 1) void k_bwd_fused3(const __hip_bfloat16* __restrict__ Emb,  // [32768,512] bf16
                                                       const __hip_bfloat16* __restrict__ WiTb, // [3072,512]
                                                       const float* __restrict__ BiasB,         // [3072]
                                                       const float* __restrict__ hTW,           // [64,3072]
                                                       __hip_bfloat16* __restrict__ Hs,
                                                       float* __restrict__ c2state,             // [64,768]
                                                       int chunk) {
  __shared__ __align__(16) unsigned short wlds[96 * EROW];        // 99,840 B weights
  __shared__ __align__(16) unsigned short emb_s[2][16][EROW];     // 33,280 B (double buf)
  __shared__ float g_lds[4][16][26];                              //  6,656 B (tot 139,776)

  const int bx = blockIdx.x;
  const int group = bx >> 5;           // 8 groups x 8 batch rows
  const int slice = bx & 31;           // cols [24*slice, 24*slice+24)
  const int r0 = group * 8;
  const int j0 = slice * SLW;
  const int tid = threadIdx.x;
  const int w = tid >> 6;              // wave = gate (r,f,g,o)
  const int lane = tid & 63;
  const int q = lane >> 4, lr = lane & 15;
  const int base = chunk * CHUNK;

  // stage Wi_b slice once: row r = gate*24+n <- WiTb[gate*768 + j0 + n][0..512)
  for (int c = tid; c < 96 * 64; c += 256) {
    const int r = c >> 6, k8 = c & 63;
    const int gate = r / SLW, n = r % SLW;
    *(float4*)(wlds + (size_t)r * EROW + k8 * 8) =
        *(const float4*)(WiTb + (size_t)(gate * H_DIM + j0 + n) * E_DIM + k8 * 8);
  }

  // scan ownership (tid<64): (rr, col0..col0+2)
  const int rr = tid >> 3, wloc = tid & 7, col0 = 3 * wloc;
  float hw0[3], hw1[3], hw2[3], hw3[3], c2r[3] = {0.f, 0.f, 0.f};
  if (tid < 64) {
    const int b = r0 + rr;
    #pragma unroll
    for (int j = 0; j < 3; ++j) {
      const int n = j0 + col0 + j;
      hw0[j] = BiasB[n]        + hTW[(size_t)b * G4 + n];
      hw1[j] = BiasB[768 + n]  + hTW[(size_t)b * G4 + 768 + n];
      hw2[j] = BiasB[1536 + n] + hTW[(size_t)b * G4 + 1536 + n];
      hw3[j] = BiasB[2304 + n] + hTW[(size_t)b * G4 + 2304 + n];
      c2r[j] = c2state[(size_t)b * H_DIM + n];
    }
  }
  const int wn0 = lr;                  // n-tile 0: cols 0..15
  const int wn1 = 16 + (lr & 7);       // n-tile 1: cols 16..23 (lanes lr>=8 duplicate)
  const unsigned short* wb0 = wlds + (size_t)(w * SLW + wn0) * EROW;
  const unsigned short* wb1 = wlds + (size_t)(w * SLW + wn1) * EROW;

  // prefetch lane constants: m-row a = [0..7]=step 2t+1, [8..15]=step 2t; batch a&7
  int aa[4], kk8[4];
  #pragma unroll
  for (int i = 0; i < 4; ++i) { aa[i] = (tid + 256 * i) >> 6; kk8[i] = (tid + 256 * i) & 63; }

  bf16x8 pf0, pf1, pf2, pf3;
#define PF_LOAD(t) { \
    pf0 = *(const bf16x8*)(Emb + ((size_t)(base + 2*(t)+1-(aa[0]>>3)) * B_DIM + r0 + (aa[0]&7)) * E_DIM + kk8[0]*8); \
    pf1 = *(const bf16x8*)(Emb + ((size_t)(base + 2*(t)+1-(aa[1]>>3)) * B_DIM + r0 + (aa[1]&7)) * E_DIM + kk8[1]*8); \
    pf2 = *(const bf16x8*)(Emb + ((size_t)(base + 2*(t)+1-(aa[2]>>3)) * B_DIM + r0 + (aa[2]&7)) * E_DIM + kk8[2]*8); \
    pf3 = *(const bf16x8*)(Emb + ((size_t)(base + 2*(t)+1-(aa[3]>>3)) * B_DIM + r0 + (aa[3]&7)) * E_DIM + kk8[3]*8); }

  PF_LOAD(CHUNK / 2 - 1);

  int buf = 0;
  for (int t = CHUNK / 2 - 1; t >= 0; --t) {
    // write prefetched group t into emb_s[buf]
    *(bf16x8*)&emb_s[buf][aa[0]][kk8[0] * 8] = pf0;
    *(bf16x8*)&emb_s[buf][aa[1]][kk8[1] * 8] = pf1;
    *(bf16x8*)&emb_s[buf][aa[2]][kk8[2] * 8] = pf2;
    *(bf16x8*)&emb_s[buf][aa[3]][kk8[3] * 8] = pf3;
    // issue next group's loads: in flight across B1 + GEMM
    if (t > 0) PF_LOAD(t - 1);
    __syncthreads();   // B1: emb_s[buf] + (first iter) wlds staged

    // GEMM: gate w, [16 m x 512 k x 24 n]; m-rows 0..7 = step 2t+1, 8..15 = step 2t
    f32x4 a0 = {0.f, 0.f, 0.f, 0.f};
    f32x4 a1 = {0.f, 0.f, 0.f, 0.f};
    #pragma unroll
    for (int kt = 0; kt < 16; ++kt) {
      const int ko = kt * 32 + q * 8;
      const bf16x8 av = *(const bf16x8*)&emb_s[buf][lr][ko];
      const bf16x8 b0 = *(const bf16x8*)(wb0 + ko);
      const bf16x8 b1 = *(const bf16x8*)(wb1 + ko);
      a0 = __builtin_amdgcn_mfma_f32_16x16x32_bf16(av, b0, a0, 0, 0, 0);
      a1 = __builtin_amdgcn_mfma_f32_16x16x32_bf16(av, b1, a1, 0, 0, 0);
    }
    #pragma unroll
    for (int i = 0; i < 4; ++i) g_lds[w][q * 4 + i][lr] = a0[i];
    if (lr < 8) {
      #pragma unroll
      for (int i = 0; i < 4; ++i) g_lds[w][q * 4 + i][16 + lr] = a1[i];
    }
    __syncthreads();   // B2: gates ready

    // scan: step 2t+1 (m=rr) then step 2t (m=8+rr), descending
    if (tid < 64) {
      #pragma unroll
      for (int st = 0; st < 2; ++st) {
        const int gs = base + 2 * t + 1 - st;
        const int m = st * 8 + rr;
        unsigned short hb[3];
        #pragma unroll
        for (int j = 0; j < 3; ++j) {
          const float rv = sigmf_(g_lds[0][m][col0 + j] + hw0[j]);
          const float fv = sigmf_(g_lds[1][m][col0 + j] + hw1[j]);
          const float gv = tanhf2(g_lds[2][m][col0 + j] + hw2[j]);
          const float ov = sigmf_(g_lds[3][m][col0 + j] + hw3[j]);
          c2r[j] = fv * c2r[j] + rv * gv;
          hb[j] = packbf(ov * tanhf2(c2r[j]));
        }
        unsigned short* hsp = (unsigned short*)(Hs + ((size_t)gs * B_DIM + r0 + rr) * H2
                                                + H_DIM + j0 + col0);
        hsp[0] = hb[0]; hsp[1] = hb[1]; hsp[2] = hb[2];
      }
    }
    buf ^= 1;
    // no trailing barrier: g_lds rewritten only after next B1; emb_s WAR covered
    // by the two barriers of the intervening iteration (double buffer).
  }
#undef PF_LOAD

  if (tid < 64) {
    #pragma unroll
    for (int j = 0; j < 3; ++j)
      c2state[(size_t)(r0 + rr) * H_DIM + j0 + col0 + j] = c2r[j];
  }
}

// ---------------- standalone backward scan over materialized X (fallback) ----------------
__global__ __launch_bounds__(256) void k_bwd_scan(const __hip_bfloat16* __restrict__ X,
                                                  const float* __restrict__ hTW,
                                                  __hip_bfloat16* __restrict__ Hs,
                                                  float* __restrict__ c2state,
                                                  int chunk) {
  const int t = blockIdx.x * 256 + threadIdx.x;    // 49152
  const int b = t / H_DIM;
  const int j = t % H_DIM;
  const int base = chunk * CHUNK;
  const float hw0 = hTW[(size_t)b * G4 + j];
  const float hw1 = hTW[(size_t)b * G4 + 768 + j];
  const float hw2 = hTW[(size_t)b * G4 + 1536 + j];
  const float hw3 = hTW[(size_t)b * G4 + 2304 + j];
  float c2 = c2state[t];
  for (int s = CHUNK - 1; s >= 0; --s) {
    const size_t xb = ((size_t)s * B_DIM + b) * G4 + j;
    const float r = sigmf_(__bfloat162float(X[xb]) + hw0);
    const float f = sigmf_(__bfloat162float(X[xb + 768]) + hw1);
    const float g = tanhf2(__bfloat162float(X[xb + 1536]) + hw2);
    const float o = sigmf_(__bfloat162float(X[xb + 2304]) + hw3);
    c2 = f * c2 + r * g;
    Hs[((size_t)(base + s) * B_DIM + b) * H2 + H_DIM + j] = __float2bfloat16(o * tanhf2(c2));
  }
  c2state[t] = c2;
}

// ---------------- host launcher ----------------
extern "C" void kernel_launch(void* const* d_in, const int* in_sizes, int n_in,
                              void* d_out, int out_size, void* d_ws, size_t ws_size,
                              hipStream_t stream) {
  const int*   tokens = (const int*)d_in[0];
  const float* emb    = (const float*)d_in[2];
  const float* Wi_f   = (const float*)d_in[3];
  const float* bi_f   = (const float*)d_in[4];
  const float* Wh_f   = (const float*)d_in[5];
  const float* bh_f   = (const float*)d_in[6];
  const float* Wi_b   = (const float*)d_in[7];
  const float* bi_b   = (const float*)d_in[8];
  const float* Wh_b   = (const float*)d_in[9];
  const float* bh_b   = (const float*)d_in[10];
  const float* Wout   = (const float*)d_in[11];
  const float* bout   = (const float*)d_in[12];
  float* out = (float*)d_out;
  char* ws = (char*)d_ws;

  size_t off = 0;
  auto alloc = [&](size_t bytes) { size_t o = off; off += (bytes + 255) & ~(size_t)255; return o; };
  const size_t oHs    = alloc((size_t)M_ROWS * H2 * 2);        // 100.7 MB
  const size_t oX0    = alloc((size_t)CM * G4 * 2);            // 50.3 MB
  const size_t oWhTf  = alloc((size_t)G4 * H_DIM * 2);         // 4.7 MB
  const size_t oWiTf  = alloc((size_t)G4 * E_DIM * 2);         // 3.1 MB
  const size_t oWiTb  = alloc((size_t)G4 * E_DIM * 2);         // 3.1 MB
  const size_t oBiasF = alloc((size_t)G4 * 4);
  const size_t oBiasB = alloc((size_t)G4 * 4);
  const size_t oHbuf  = alloc((size_t)2 * PSTR * 8);           // 256 KB packed h
  const size_t oCst   = alloc((size_t)B_DIM * H_DIM * 4);
  const size_t oHT    = alloc((size_t)B_DIM * H_DIM * 4);
  const size_t oHTW   = alloc((size_t)B_DIM * G4 * 4);
  const size_t oC2    = alloc((size_t)B_DIM * H_DIM * 4);
  const size_t oX1    = alloc((size_t)CM * G4 * 2);            // 50.3 MB (overlap only)
  const bool overlap = (off <= ws_size);                       // ~214 MB
  const size_t oEmb   = alloc((size_t)M_ROWS * E_DIM * 2);     // 33.6 MB (tier A only)
  const bool tierA = (off <= ws_size);                         // ~248 MB
  (void)in_sizes; (void)n_in; (void)out_size;

  __hip_bfloat16* Hs   = (__hip_bfloat16*)(ws + oHs);
  __hip_bfloat16* X0   = (__hip_bfloat16*)(ws + oX0);
  __hip_bfloat16* X1   = overlap ? (__hip_bfloat16*)(ws + oX1) : X0;
  __hip_bfloat16* Emb  = tierA ? (__hip_bfloat16*)(ws + oEmb) : (__hip_bfloat16*)nullptr;
  __hip_bfloat16* WhTf = (__hip_bfloat16*)(ws + oWhTf);
  __hip_bfloat16* WiTf = (__hip_bfloat16*)(ws + oWiTf);
  __hip_bfloat16* WiTb = (__hip_bfloat16*)(ws + oWiTb);
  float*          BiasF= (float*)(ws + oBiasF);
  float*          BiasB= (float*)(ws + oBiasB);
  ull_t*          Hbuf = (ull_t*)(ws + oHbuf);
  float*          Cst  = (float*)(ws + oCst);
  float*          HT   = (float*)(ws + oHT);
  float*          HTW  = (float*)(ws + oHTW);
  float*          C2   = (float*)(ws + oC2);

  hipMemsetAsync(ws + oHbuf, 0, (size_t)2 * PSTR * 8, stream);   // h_0 = 0, tag 0
  hipMemsetAsync(ws + oCst, 0, (size_t)B_DIM * H_DIM * 4, stream);
  hipMemsetAsync(ws + oC2, 0, (size_t)B_DIM * H_DIM * 4, stream);

  if (tierA)
    k_gather<<<8192, 256, 0, stream>>>(tokens, emb, Emb);
  k_transpose_cast<<<dim3(96, 24), 256, 0, stream>>>(Wh_f, WhTf, 768, 3072);
  k_transpose_cast<<<dim3(96, 16), 256, 0, stream>>>(Wi_f, WiTf, 512, 3072);
  k_transpose_cast<<<dim3(96, 16), 256, 0, stream>>>(Wi_b, WiTb, 512, 3072);
  k_bias<<<12, 256, 0, stream>>>(bi_f, bh_f, BiasF);
  k_bias<<<12, 256, 0, stream>>>(bi_b, bh_b, BiasB);

  if (overlap && tierA) {
    // prologue: X chunk 0 (forward)
    k_gemm_e<<<NTILES, 256, 0, stream>>>(Emb, WiTf, BiasF, X0);
    auto EA = [&](int c) { return Emb + (size_t)c * CM * E_DIM; };
    // forward: scan(c) || X-GEMM(next); fwd c reads buf[c&1]. chunk 3: scan only.
    k_fwd_fused<<<240, 256, 0, stream>>>(X0, WhTf, Hbuf, Hs, Cst, HT, 0,
                                         EA(1), tokens, emb, WiTf, BiasF, X1);
    k_fwd_fused<<<240, 256, 0, stream>>>(X1, WhTf, Hbuf, Hs, Cst, HT, 1,
                                         EA(2), tokens, emb, WiTf, BiasF, X0);
    k_fwd_fused<<<240, 256, 0, stream>>>(X0, WhTf, Hbuf, Hs, Cst, HT, 2,
                                         EA(3), tokens, emb, WiTf, BiasF, X1);
    k_fwd_fused<<<128, 256, 0, stream>>>(X1, WhTf, Hbuf, Hs, Cst, HT, 3,
                                         EA(0), tokens, emb, WiTf, BiasF, X0);
    k_hTW<<<dim3(12, 64), 256, 0, stream>>>(HT, Wh_b, HTW);
    // backward: fused GEMM+scan on the full machine (no X materialization)
    k_bwd_fused3<<<256, 256, 0, stream>>>(Emb, WiTb, BiasB, HTW, Hs, C2, 3);
    k_bwd_fused3<<<256, 256, 0, stream>>>(Emb, WiTb, BiasB, HTW, Hs, C2, 2);
    k_bwd_fused3<<<256, 256, 0, stream>>>(Emb, WiTb, BiasB, HTW, Hs, C2, 1);
    k_bwd_fused3<<<256, 256, 0, stream>>>(Emb, WiTb, BiasB, HTW, Hs, C2, 0);
    k_out<<<4096, 256, 0, stream>>>(Hs, Wout, bout, tokens, out);
  } else if (overlap) {
    // Tier B: forward fused with gather workers; backward via materialized X
    k_gemm_g<<<NTILES, 256, 0, stream>>>(tokens, emb, WiTf, BiasF, X0);
    k_fwd_fused<<<240, 256, 0, stream>>>(X0, WhTf, Hbuf, Hs, Cst, HT, 0,
                                         nullptr, tokens + 1 * CM, emb, WiTf, BiasF, X1);
    k_fwd_fused<<<240, 256, 0, stream>>>(X1, WhTf, Hbuf, Hs, Cst, HT, 1,
                                         nullptr, tokens + 2 * CM, emb, WiTf, BiasF, X0);
    k_fwd_fused<<<240, 256, 0, stream>>>(X0, WhTf, Hbuf, Hs, Cst, HT, 2,
                                         nullptr, tokens + 3 * CM, emb, WiTf, BiasF, X1);
    k_fwd_fused<<<240, 256, 0, stream>>>(X1, WhTf, Hbuf, Hs, Cst, HT, 3,
                                         nullptr, tokens + 3 * CM, emb, WiTb, BiasB, X0);
    k_hTW<<<dim3(12, 64), 256, 0, stream>>>(HT, Wh_b, HTW);
    k_bwd_scan<<<192, 256, 0, stream>>>(X0, HTW, Hs, C2, 3);
    for (int c = 2; c >= 0; --c) {
      k_gemm_g<<<NTILES, 256, 0, stream>>>(tokens + (size_t)c * CM, emb, WiTb, BiasB, X1);
      k_bwd_scan<<<192, 256, 0, stream>>>(X1, HTW, Hs, C2, c);
    }
    k_out<<<4096, 256, 0, stream>>>(Hs, Wout, bout, tokens, out);
  } else {
    // sequential fallback (single X buffer, gather-fused)
    for (int c = 0; c < 4; ++c) {
      k_gemm_g<<<NTILES, 256, 0, stream>>>(tokens + (size_t)c * CM, emb, WiTf, BiasF, X0);
      k_fwd_fused<<<128, 256, 0, stream>>>(X0, WhTf, Hbuf, Hs, Cst, HT, c,
                                           nullptr, tokens, emb, WiTf, BiasF, X0);
    }
    k_hTW<<<dim3(12, 64), 256, 0, stream>>>(HT, Wh_b, HTW);
    for (int c = 3; c >= 0; --c) {
      k_gemm_g<<<NTILES, 256, 0, stream>>>(tokens + (size_t)c * CM, emb, WiTb, BiasB, X0);
      k_bwd_scan<<<192, 256, 0, stream>>>(X0, HTW, Hs, C2, c);
    }
    k_out<<<4096, 256, 0, stream>>>(Hs, Wout, bout, tokens, out);
  }
}